// Round 11
// baseline (213.596 us; speedup 1.0000x reference)
//
#include <hip/hip_runtime.h>
#include <cstddef>
#include <cstdint>

#define NB 2
#define L_SEQ 2048
#define DM 512
#define DS 16
#define DI 1024
#define NC 64
#define CL (L_SEQ/NC)   // 32

typedef __attribute__((ext_vector_type(4))) float f32x4;
typedef __attribute__((ext_vector_type(8))) short bf16x8;

__device__ __forceinline__ float softplus_f(float x) {
  return (x > 20.f) ? x : log1pf(expf(x));
}
__device__ __forceinline__ float silu_f(float x) {
  return x / (1.f + expf(-x));
}
__device__ __forceinline__ ushort f2bf(float f) {
  uint32_t u = __float_as_uint(f);
  return (ushort)((u + 0x7fffu + ((u >> 16) & 1u)) >> 16);
}
__device__ __forceinline__ float bf2f(ushort h) {
  return __uint_as_float(((uint32_t)h) << 16);
}

__device__ __forceinline__ void gload16(const void* g, ushort* lds_wave_base) {
  __builtin_amdgcn_global_load_lds(
      (const __attribute__((address_space(1))) void*)g,
      (__attribute__((address_space(3))) void*)lds_wave_base, 16, 0, 0);
}

// fp32 -> bf16 hi/lo split, vectorized by 4
__global__ __launch_bounds__(256) void split_bf16(
    const float* __restrict__ in, ushort* __restrict__ hi,
    ushort* __restrict__ lo, int n4) {
  int i = blockIdx.x * 256 + threadIdx.x;
  if (i >= n4) return;
  float4 v = ((const float4*)in)[i];
  ushort h0 = f2bf(v.x), h1 = f2bf(v.y), h2 = f2bf(v.z), h3 = f2bf(v.w);
  ((ushort4*)hi)[i] = make_ushort4(h0, h1, h2, h3);
  ((ushort4*)lo)[i] = make_ushort4(
      f2bf(v.x - bf2f(h0)), f2bf(v.y - bf2f(h1)),
      f2bf(v.z - bf2f(h2)), f2bf(v.w - bf2f(h3)));
}

// ---- split-bf16 MFMA GEMM, fat 64x32 wave tiles (MR=4, NR=2), BN=128 ----
// BM=128: 512 thr (8 waves, 2x4), 64KB LDS -> 2 blocks/CU.
// BM=64 : 256 thr (4 waves, 1x4), 48KB LDS -> 3 blocks/CU.
// Per wave-K-step: 12 ds_read_b128 feed 24 MFMA (vs 8:12 at 32x32 tiles).
// 2-buffer LDS, 1-deep prefetch, one __syncthreads per K-step (R10-proven loop).
// ACT==1: cols<1024 -> softplus(+bias) into C; cols 1024..1039 -> Bmout; rest discard.
template <int BM, int ACT>
__global__ __launch_bounds__(BM * 4, (BM == 128) ? 4 : 3) void gemm_mfma(
    const ushort* __restrict__ Ahi, const ushort* __restrict__ Alo, int lda,
    const ushort* __restrict__ Bhi, const ushort* __restrict__ Blo, int ldb,
    const float* __restrict__ bias, float* __restrict__ C, int ldc,
    float* __restrict__ Bmout, int K) {
  constexpr int BN = 128;
  constexpr int AT = BM * 32;        // ushorts per A tile (hi or lo)
  constexpr int BT = BN * 32;        // 4096 ushorts
  constexpr int BUF = 2 * AT + 2 * BT;
  constexpr int MR = 4, NR = 2;
  __shared__ __align__(16) ushort lds[2 * BUF];

  const int tid = threadIdx.x;
  const int lane = tid & 63;
  const int wave = tid >> 6;
  const int wr = wave >> 2;          // 0..BM/64-1 (row slot, 64 rows)
  const int wc = wave & 3;           // 0..3       (col slot, 32 cols)

  // bijective XCD swizzle (all launches have nwg % 8 == 0)
  const int nx = gridDim.x;
  const int nwg = nx * gridDim.y;
  int bid = blockIdx.y * nx + blockIdx.x;
  bid = (bid & 7) * (nwg >> 3) + (bid >> 3);
  const int m0 = (bid / nx) * BM;
  const int n0 = (bid % nx) * BN;

  // staging: thread -> row ra = tid>>2, k-slot (tid&3), pre-swizzled source
  // (row bits 1-2 select the XOR -> rows r and r+64 share it; frag reads match)
  const int ra = tid >> 2;
  const int kga = (tid & 3) ^ ((ra >> 1) & 3);
  const size_t aoff  = (size_t)(m0 + ra) * lda + kga * 8;
  const size_t boff0 = (size_t)(n0 + ra) * ldb + kga * 8;
  const size_t boff1 = (size_t)(n0 + ra + 64) * ldb + kga * 8;  // BM==64 only

  // fragment reads: k-slot = fq ^ ((row>>1)&3), row bits 1-2 == fr bits 1-2
  const int fr = lane & 15, fq = lane >> 4;
  const int kswz = fq ^ ((fr >> 1) & 3);
  int aoffs[MR], boffs[NR];
#pragma unroll
  for (int m = 0; m < MR; m++) aoffs[m] = (wr * 64 + m * 16 + fr) * 32 + kswz * 8;
#pragma unroll
  for (int n = 0; n < NR; n++) boffs[n] = (wc * 32 + n * 16 + fr) * 32 + kswz * 8;

  f32x4 acc[MR][NR];
#pragma unroll
  for (int m = 0; m < MR; m++)
#pragma unroll
    for (int n = 0; n < NR; n++) acc[m][n] = (f32x4){0.f, 0.f, 0.f, 0.f};

  const int nsteps = K >> 5;

#define STAGE(base, kk)                                                     \
  {                                                                         \
    ushort* bp = (base);                                                    \
    gload16(Ahi + aoff + (kk), bp + wave * 512);                            \
    gload16(Alo + aoff + (kk), bp + AT + wave * 512);                       \
    gload16(Bhi + boff0 + (kk), bp + 2 * AT + wave * 512);                  \
    gload16(Blo + boff0 + (kk), bp + 2 * AT + BT + wave * 512);             \
    if constexpr (BM == 64) {                                               \
      gload16(Bhi + boff1 + (kk), bp + 2 * AT + 2048 + wave * 512);         \
      gload16(Blo + boff1 + (kk), bp + 2 * AT + BT + 2048 + wave * 512);    \
    }                                                                       \
  }

#define COMPUTE(base)                                                          \
  {                                                                            \
    const ushort* cp = (base);                                                 \
    bf16x8 ah[MR], al[MR], bh[NR], bl[NR];                                     \
    _Pragma("unroll")                                                          \
    for (int m = 0; m < MR; m++) ah[m] = *(const bf16x8*)(cp + aoffs[m]);      \
    _Pragma("unroll")                                                          \
    for (int m = 0; m < MR; m++) al[m] = *(const bf16x8*)(cp + AT + aoffs[m]); \
    _Pragma("unroll")                                                          \
    for (int n = 0; n < NR; n++) bh[n] = *(const bf16x8*)(cp + 2 * AT + boffs[n]); \
    _Pragma("unroll")                                                          \
    for (int n = 0; n < NR; n++) bl[n] = *(const bf16x8*)(cp + 2 * AT + BT + boffs[n]); \
    _Pragma("unroll")                                                          \
    for (int m = 0; m < MR; m++)                                               \
      _Pragma("unroll")                                                        \
      for (int n = 0; n < NR; n++)                                             \
        acc[m][n] = __builtin_amdgcn_mfma_f32_16x16x32_bf16(ah[m], bh[n], acc[m][n], 0, 0, 0); \
    _Pragma("unroll")                                                          \
    for (int m = 0; m < MR; m++)                                               \
      _Pragma("unroll")                                                        \
      for (int n = 0; n < NR; n++)                                             \
        acc[m][n] = __builtin_amdgcn_mfma_f32_16x16x32_bf16(al[m], bh[n], acc[m][n], 0, 0, 0); \
    _Pragma("unroll")                                                          \
    for (int m = 0; m < MR; m++)                                               \
      _Pragma("unroll")                                                        \
      for (int n = 0; n < NR; n++)                                             \
        acc[m][n] = __builtin_amdgcn_mfma_f32_16x16x32_bf16(ah[m], bl[n], acc[m][n], 0, 0, 0); \
  }

  STAGE(lds, 0);
  __syncthreads();                       // drain: buf0 ready
  for (int t = 0; t < nsteps; ++t) {
    if (t + 1 < nsteps) STAGE(lds + ((t + 1) & 1) * BUF, (t + 1) << 5);
    COMPUTE(lds + (t & 1) * BUF);
    __syncthreads();                     // all reads of buf[t] done; buf[t+1] staged
  }
#undef STAGE
#undef COMPUTE

#pragma unroll
  for (int m = 0; m < MR; m++) {
    const int row = m0 + wr * 64 + m * 16 + fq * 4;
#pragma unroll
    for (int n = 0; n < NR; n++) {
      const int col = n0 + wc * 32 + n * 16 + fr;
      if (ACT == 1) {
        if (col < DI) {                  // delta columns
          const float bcol = bias[col];
#pragma unroll
          for (int j = 0; j < 4; j++)
            C[(size_t)(row + j) * ldc + col] = softplus_f(acc[m][n][j] + bcol);
        } else if (col < DI + DS) {      // Bmat columns
#pragma unroll
          for (int j = 0; j < 4; j++)
            Bmout[(size_t)(row + j) * DS + (col - DI)] = acc[m][n][j];
        }                                // else: pad columns, discard
      } else {
#pragma unroll
        for (int j = 0; j < 4; j++)
          C[(size_t)(row + j) * ldc + col] = acc[m][n][j];
      }
    }
  }
}

// depthwise causal conv (k=4) + SiLU; emits h fp32 and bf16 hi/lo split
__global__ __launch_bounds__(256) void conv_silu_kernel(
    const float* __restrict__ xz, const float* __restrict__ conv_w,
    const float* __restrict__ conv_b, float* __restrict__ h,
    ushort* __restrict__ h_hi, ushort* __restrict__ h_lo) {
  const int idx = blockIdx.x * 256 + threadIdx.x;
  const int c = idx & (DI - 1);
  const int r = idx >> 10;
  const int l = r & (L_SEQ - 1);
  const float w0 = conv_w[c * 4 + 0];
  const float w1 = conv_w[c * 4 + 1];
  const float w2 = conv_w[c * 4 + 2];
  const float w3 = conv_w[c * 4 + 3];
  const float* xp = xz + (size_t)r * (2 * DI) + c;
  float acc = conv_b[c];
  if (l >= 3) acc += xp[-3 * 2 * DI] * w0;
  if (l >= 2) acc += xp[-2 * 2 * DI] * w1;
  if (l >= 1) acc += xp[-1 * 2 * DI] * w2;
  acc += xp[0] * w3;
  const float hv = silu_f(acc);
  h[idx] = hv;
  const ushort hh = f2bf(hv);
  h_hi[idx] = hh;
  h_lo[idx] = f2bf(hv - bf2f(hh));
}

// ---- chunked selective scan, channel-per-thread ----
__global__ __launch_bounds__(256) void scan_phase1(
    const float* __restrict__ delta, const float* __restrict__ h,
    const float* __restrict__ Bm, const float* __restrict__ A_log,
    float* __restrict__ aprod, float* __restrict__ blocal) {
  __shared__ float sB[CL * DS];  // 2KB
  const int tid = threadIdx.x;
  const int bid = blockIdx.x;
  const int cblk = bid & 3;
  const int chunk = (bid >> 2) & (NC - 1);
  const int b = bid >> 8;
  const int c = cblk * 256 + tid;
  const size_t row0 = (size_t)b * L_SEQ + chunk * CL;
  ((float2*)sB)[tid] = ((const float2*)(Bm + row0 * DS))[tid];
  __syncthreads();

  float Acs[DS], state[DS];
#pragma unroll
  for (int s = 0; s < DS; s += 4) {
    float4 al = *(const float4*)(A_log + (size_t)c * DS + s);
    Acs[s + 0] = -__expf(al.x);
    Acs[s + 1] = -__expf(al.y);
    Acs[s + 2] = -__expf(al.z);
    Acs[s + 3] = -__expf(al.w);
    state[s + 0] = 0.f; state[s + 1] = 0.f; state[s + 2] = 0.f; state[s + 3] = 0.f;
  }
  const float* dp = delta + row0 * DI + c;
  const float* hp = h + row0 * DI + c;
  float sdt = 0.f;
  for (int t = 0; t < CL; ++t) {
    const float dt = dp[(size_t)t * DI];
    const float ht = hp[(size_t)t * DI];
    const float dth = dt * ht;
    sdt += dt;
#pragma unroll
    for (int s = 0; s < DS; ++s)
      state[s] = __expf(dt * Acs[s]) * state[s] + dth * sB[t * DS + s];
  }
  const size_t o = (((size_t)b * NC + chunk) * DI + c) * DS;
#pragma unroll
  for (int s = 0; s < DS; s += 4) {
    *(float4*)(aprod + o + s) = make_float4(
        __expf(Acs[s] * sdt), __expf(Acs[s + 1] * sdt),
        __expf(Acs[s + 2] * sdt), __expf(Acs[s + 3] * sdt));
    *(float4*)(blocal + o + s) = make_float4(state[s], state[s + 1], state[s + 2], state[s + 3]);
  }
}

// serial scan over chunk summaries; writes sinit IN PLACE over aprod
__global__ __launch_bounds__(256) void scan_phase2(
    float* __restrict__ aprod, const float* __restrict__ blocal) {
  const int idx = blockIdx.x * 256 + threadIdx.x;  // NB*DI*DS = 32768
  const int b = idx >> 14;
  const int cs = idx & 16383;
  float st = 0.f;
  for (int ch = 0; ch < NC; ++ch) {
    const size_t o = (size_t)(b * NC + ch) * (DI * DS) + cs;
    const float a = aprod[o];
    const float bl = blocal[o];
    aprod[o] = st;   // sinit for this chunk
    st = a * st + bl;
  }
}

// phase3: rerun chunk with init state; fused gate + bf16 hi/lo split of y.
__global__ __launch_bounds__(256) void scan_phase3(
    const float* __restrict__ delta, const float* __restrict__ h,
    const float* __restrict__ Bm, const float* __restrict__ A_log,
    const float* __restrict__ sinit, float* __restrict__ xz,
    const float* __restrict__ Dp) {
  __shared__ float sB[CL * DS];
  const int tid = threadIdx.x;
  const int bid = blockIdx.x;
  const int cblk = bid & 3;
  const int chunk = (bid >> 2) & (NC - 1);
  const int b = bid >> 8;
  const int c = cblk * 256 + tid;
  const size_t row0 = (size_t)b * L_SEQ + chunk * CL;
  ((float2*)sB)[tid] = ((const float2*)(Bm + row0 * DS))[tid];
  __syncthreads();

  float Acs[DS], state[DS];
  const size_t o = (((size_t)b * NC + chunk) * DI + c) * DS;
#pragma unroll
  for (int s = 0; s < DS; s += 4) {
    float4 al = *(const float4*)(A_log + (size_t)c * DS + s);
    Acs[s + 0] = -__expf(al.x);
    Acs[s + 1] = -__expf(al.y);
    Acs[s + 2] = -__expf(al.z);
    Acs[s + 3] = -__expf(al.w);
    float4 sv = *(const float4*)(sinit + o + s);
    state[s + 0] = sv.x; state[s + 1] = sv.y; state[s + 2] = sv.z; state[s + 3] = sv.w;
  }
  const float* dp = delta + row0 * DI + c;
  const float* hp = h + row0 * DI + c;
  const float* zp = xz + row0 * (2 * DI) + DI + c;
  ushort* yrow = (ushort*)(xz + row0 * (2 * DI)) + c;  // row stride 4096 ushorts
  const float Dc = Dp[c];
  for (int t = 0; t < CL; ++t) {
    const float dt = dp[(size_t)t * DI];
    const float ht = hp[(size_t)t * DI];
    const float z = zp[(size_t)t * (2 * DI)];
    const float dth = dt * ht;
    float yv = 0.f;
#pragma unroll
    for (int s = 0; s < DS; ++s) {
      const float bt = sB[t * DS + s];
      state[s] = __expf(dt * Acs[s]) * state[s] + dth * bt;
      yv += state[s] * bt;
    }
    const float g = (yv + Dc * ht) * silu_f(z);
    const ushort gh = f2bf(g);
    yrow[(size_t)t * 4096] = gh;
    yrow[(size_t)t * 4096 + 1024] = f2bf(g - bf2f(gh));
  }
}

extern "C" void kernel_launch(void* const* d_in, const int* in_sizes, int n_in,
                              void* d_out, int out_size, void* d_ws, size_t ws_size,
                              hipStream_t stream) {
  const float* x      = (const float*)d_in[0];
  const float* W_in   = (const float*)d_in[1];
  const float* conv_w = (const float*)d_in[2];
  const float* conv_b = (const float*)d_in[3];
  const float* W_x    = (const float*)d_in[4];
  const float* W_dt   = (const float*)d_in[5];
  const float* b_dt   = (const float*)d_in[6];
  const float* A_log  = (const float*)d_in[7];
  const float* D_par  = (const float*)d_in[8];
  const float* W_out  = (const float*)d_in[9];
  float* out = (float*)d_out;

  const int rows = NB * L_SEQ;  // 4096

  // ws layout (floats) — ~87 MB total
  float* xz     = (float*)d_ws;                       // 8M floats
  float* h      = xz + (size_t)(8u << 20);            // 4M
  float* delta  = h + (size_t)(4u << 20);             // 4M
  float* Bm     = delta + (size_t)(4u << 20);         // 64K floats ([4096][16])
  // fused GEMM2 weight: [1152][1024] bf16 hi + lo
  // (rows 0-1023 W_dt, 1024-1039 W_x[16:32], 1040-1151 pad/garbage - cols discarded)
  ushort* W2hi  = (ushort*)(Bm + (size_t)(64u << 10));
  ushort* W2lo  = W2hi + (size_t)1152 * 1024;
  ushort* Wout_hi = W2lo + (size_t)1152 * 1024;
  ushort* Wout_lo = Wout_hi + (size_t)(512u << 10);
  float* xreg   = (float*)(Wout_lo + (size_t)(512u << 10));  // overlay region
  ushort* x_hi  = (ushort*)xreg;
  ushort* x_lo  = x_hi + (size_t)(2u << 20);
  ushort* Win_hi = x_lo + (size_t)(2u << 20);
  ushort* Win_lo = Win_hi + (size_t)(1u << 20);
  ushort* h_hi  = (ushort*)xreg;                      // overlay (x/W_in dead after GEMM1)
  ushort* h_lo  = h_hi + (size_t)(4u << 20);
  float* aprod  = xreg;                               // overlay (h_hi/h_lo dead after GEMM2)
  float* blocal = aprod + (size_t)(2u << 20);         // NB*NC*DI*DS = 2M floats each
  ushort* y_hi  = (ushort*)xz;                        // xi-cols overlay, lda 4096
  ushort* y_lo  = y_hi + 1024;

  // 0) bf16 hi/lo splits
  split_bf16<<<2048, 256, 0, stream>>>(x, x_hi, x_lo, rows * DM / 4);
  split_bf16<<<1024, 256, 0, stream>>>(W_in, Win_hi, Win_lo, 2 * DI * DM / 4);
  split_bf16<<<1024, 256, 0, stream>>>(W_dt, W2hi, W2lo, DI * DI / 4);
  split_bf16<<<16, 256, 0, stream>>>(W_x + DS * DI,
      W2hi + (size_t)DI * DI, W2lo + (size_t)DI * DI, DS * DI / 4);
  split_bf16<<<512, 256, 0, stream>>>(W_out, Wout_hi, Wout_lo, DM * DI / 4);

  // 1) xz = x @ W_in^T   M=4096 N=2048 K=512   (grid 16x32 = 512, fully resident)
  gemm_mfma<128, 0><<<dim3(16, 32), 512, 0, stream>>>(
      x_hi, x_lo, DM, Win_hi, Win_lo, DM, nullptr, xz, 2 * DI, nullptr, DM);
  // 2) conv + silu -> h (+ hi/lo)
  conv_silu_kernel<<<(rows * DI) / 256, 256, 0, stream>>>(xz, conv_w, conv_b, h, h_hi, h_lo);
  // 3) fused delta+Bmat GEMM: [4096]x[1152]x[1024]  (grid 9x32 = 288, fully resident)
  gemm_mfma<128, 1><<<dim3(9, 32), 512, 0, stream>>>(
      h_hi, h_lo, DI, W2hi, W2lo, DI, b_dt, delta, DI, Bm, DI);
  // 4) chunked scan
  scan_phase1<<<NB * NC * (DI / 256), 256, 0, stream>>>(delta, h, Bm, A_log, aprod, blocal);
  scan_phase2<<<(NB * DI * DS) / 256, 256, 0, stream>>>(aprod, blocal);
  scan_phase3<<<NB * NC * (DI / 256), 256, 0, stream>>>(delta, h, Bm, A_log, aprod, xz, D_par);
  // 5) out = y @ W_out^T   M=4096 N=512 K=1024   (BM=64: grid 4x64 = 256, 3 blk/CU)
  gemm_mfma<64, 0><<<dim3(4, 64), 256, 0, stream>>>(
      y_hi, y_lo, 4096, Wout_hi, Wout_lo, DI, nullptr, out, DM, nullptr, DI);
}

// Round 12
// 201.736 us; speedup vs baseline: 1.0588x; 1.0588x over previous
//
#include <hip/hip_runtime.h>
#include <cstddef>
#include <cstdint>

#define NB 2
#define L_SEQ 2048
#define DM 512
#define DS 16
#define DI 1024
#define NC 64
#define CL (L_SEQ/NC)   // 32

typedef __attribute__((ext_vector_type(4))) float f32x4;
typedef __attribute__((ext_vector_type(8))) short bf16x8;

__device__ __forceinline__ float softplus_f(float x) {
  return (x > 20.f) ? x : log1pf(expf(x));
}
__device__ __forceinline__ float silu_f(float x) {
  return x / (1.f + expf(-x));
}
__device__ __forceinline__ ushort f2bf(float f) {
  uint32_t u = __float_as_uint(f);
  return (ushort)((u + 0x7fffu + ((u >> 16) & 1u)) >> 16);
}
__device__ __forceinline__ float bf2f(ushort h) {
  return __uint_as_float(((uint32_t)h) << 16);
}

__device__ __forceinline__ void gload16(const void* g, ushort* lds_wave_base) {
  __builtin_amdgcn_global_load_lds(
      (const __attribute__((address_space(1))) void*)g,
      (__attribute__((address_space(3))) void*)lds_wave_base, 16, 0, 0);
}

__device__ __forceinline__ void split4(const float4 v, ushort4* hi, ushort4* lo) {
  ushort h0 = f2bf(v.x), h1 = f2bf(v.y), h2 = f2bf(v.z), h3 = f2bf(v.w);
  *hi = make_ushort4(h0, h1, h2, h3);
  *lo = make_ushort4(f2bf(v.x - bf2f(h0)), f2bf(v.y - bf2f(h1)),
                     f2bf(v.z - bf2f(h2)), f2bf(v.w - bf2f(h3)));
}

// one kernel, 5 segments: x, W_in, W_dt, W_x-tail, W_out  (saves 4 launches)
__global__ __launch_bounds__(256) void split_all(
    const float* __restrict__ x,    ushort* __restrict__ xh,  ushort* __restrict__ xl,
    const float* __restrict__ win,  ushort* __restrict__ wih, ushort* __restrict__ wil,
    const float* __restrict__ wdt,  ushort* __restrict__ wdh, ushort* __restrict__ wdl,
    const float* __restrict__ wx,   ushort* __restrict__ wxh, ushort* __restrict__ wxl,
    const float* __restrict__ wout, ushort* __restrict__ woh, ushort* __restrict__ wol) {
  int bi = blockIdx.x;
  const float* in; ushort* hi; ushort* lo; int i;
  if (bi < 2048)      { in = x;    hi = xh;  lo = xl;  i = bi * 256 + threadIdx.x; }
  else if (bi < 3072) { in = win;  hi = wih; lo = wil; i = (bi - 2048) * 256 + threadIdx.x; }
  else if (bi < 4096) { in = wdt;  hi = wdh; lo = wdl; i = (bi - 3072) * 256 + threadIdx.x; }
  else if (bi < 4112) { in = wx;   hi = wxh; lo = wxl; i = (bi - 4096) * 256 + threadIdx.x; }
  else                { in = wout; hi = woh; lo = wol; i = (bi - 4112) * 256 + threadIdx.x; }
  float4 v = ((const float4*)in)[i];
  ushort4 h4, l4;
  split4(v, &h4, &l4);
  ((ushort4*)hi)[i] = h4;
  ((ushort4*)lo)[i] = l4;
}

#define MFMA(a, b, c) __builtin_amdgcn_mfma_f32_16x16x32_bf16((a), (b), (c), 0, 0, 0)

// ---- 8-wave split-bf16 MFMA GEMM, 3-phase interleaved schedule (T3+T4+T5) ----
// BM=128, BN=64, 512 thr, 32x32 per-wave output (R10 geometry).
// 3 LDS buffers (72KB), 2-deep prefetch; per K-step: 3 phases
// {ds_read frag | issue stage(t+2) [P2/P3 only] | barrier | setprio(1) 4xMFMA setprio(0) | barrier};
// counted vmcnt(3) once per K-step at top -- prefetch loads stay in flight across barriers.
// ACT==1: cols<1024 -> softplus(+bias); cols 1024..1039 -> Bmout; rest discard.
template <int ACT>
__global__ __launch_bounds__(512, 4) void gemm_mfma8(
    const ushort* __restrict__ Ahi, const ushort* __restrict__ Alo, int lda,
    const ushort* __restrict__ Bhi, const ushort* __restrict__ Blo, int ldb,
    const float* __restrict__ bias, float* __restrict__ C, int ldc,
    float* __restrict__ Bmout, int K) {
  constexpr int BM = 128, BN = 64;
  constexpr int AT = BM * 32;           // 4096 ushorts (8KB)
  constexpr int BT = BN * 32;           // 2048 ushorts (4KB)
  constexpr int BUF = 2 * AT + 2 * BT;  // 24KB
  __shared__ __align__(16) ushort lds[3 * BUF];  // 72KB

  const int tid = threadIdx.x;
  const int lane = tid & 63;
  const int wave = tid >> 6;            // 0..7
  const int wr = wave >> 1;             // 0..3
  const int wc = wave & 1;              // 0..1

  // bijective XCD swizzle (all launches have nwg % 8 == 0)
  const int nx = gridDim.x;
  const int nwg = nx * gridDim.y;
  int bid = blockIdx.y * nx + blockIdx.x;
  bid = (bid & 7) * (nwg >> 3) + (bid >> 3);
  const int m0 = (bid / nx) * BM;
  const int n0 = (bid % nx) * BN;

  // A staging: thread -> row tid>>2 (0..127), k-slot (tid&3) pre-swizzled
  const int ra = tid >> 2;
  const int kga = (tid & 3) ^ ((ra >> 1) & 3);
  const size_t aoff = (size_t)(m0 + ra) * lda + kga * 8;
  // B staging: tq = tid&255 -> row tq>>2 (0..63); waves 0-3 stage Bhi, 4-7 Blo
  const int tq = tid & 255;
  const int rb = tq >> 2;
  const int kgb = (tq & 3) ^ ((rb >> 1) & 3);
  const size_t boff = (size_t)(n0 + rb) * ldb + kgb * 8;
  const ushort* Bsel = (wave < 4) ? Bhi : Blo;
  const int blds = 2 * AT + ((wave < 4) ? wave * 512 : BT + (wave - 4) * 512);

  // fragment reads: row = wr*32 + m*16 + fr; k-slot = fq ^ ((fr>>1)&3)
  const int fr = lane & 15, fq = lane >> 4;
  const int kswz = fq ^ ((fr >> 1) & 3);
  int aoffs[2], boffs[2];
#pragma unroll
  for (int m = 0; m < 2; m++) aoffs[m] = (wr * 32 + m * 16 + fr) * 32 + kswz * 8;
#pragma unroll
  for (int n = 0; n < 2; n++) boffs[n] = (wc * 32 + n * 16 + fr) * 32 + kswz * 8;

  f32x4 acc[2][2];
#pragma unroll
  for (int m = 0; m < 2; m++)
#pragma unroll
    for (int n = 0; n < 2; n++) acc[m][n] = (f32x4){0.f, 0.f, 0.f, 0.f};

  const int nsteps = K >> 5;

  // prologue: fill buf0, buf1
  gload16(Ahi + aoff + 0, lds + wave * 512);
  gload16(Alo + aoff + 0, lds + AT + wave * 512);
  gload16(Bsel + boff + 0, lds + blds);
  gload16(Ahi + aoff + 32, lds + BUF + wave * 512);
  gload16(Alo + aoff + 32, lds + BUF + AT + wave * 512);
  gload16(Bsel + boff + 32, lds + BUF + blds);

  int cur = 0;
  for (int t = 0; t < nsteps; ++t) {
    const ushort* cp = lds + cur * BUF;
    const int nxt = (cur + 2) % 3;
    ushort* np = lds + nxt * BUF;
    const bool pf = (t + 2) < nsteps;
    const int kk2 = (t + 2) << 5;
    // buf[cur] ready when <=3 outstanding (those 3 belong to buf[t+1])
    if (t + 1 < nsteps) asm volatile("s_waitcnt vmcnt(3)" ::: "memory");
    else                asm volatile("s_waitcnt vmcnt(0)" ::: "memory");
    __builtin_amdgcn_s_barrier();        // buf[cur] staged by all waves
    // ---- phase 1: hi*hi ----
    bf16x8 ah0 = *(const bf16x8*)(cp + aoffs[0]);
    bf16x8 ah1 = *(const bf16x8*)(cp + aoffs[1]);
    bf16x8 bh0 = *(const bf16x8*)(cp + 2 * AT + boffs[0]);
    bf16x8 bh1 = *(const bf16x8*)(cp + 2 * AT + boffs[1]);
    __builtin_amdgcn_sched_barrier(0);
    __builtin_amdgcn_s_setprio(1);
    acc[0][0] = MFMA(ah0, bh0, acc[0][0]);
    acc[0][1] = MFMA(ah0, bh1, acc[0][1]);
    acc[1][0] = MFMA(ah1, bh0, acc[1][0]);
    acc[1][1] = MFMA(ah1, bh1, acc[1][1]);
    __builtin_amdgcn_s_setprio(0);
    __builtin_amdgcn_s_barrier();
    // ---- phase 2: lo*hi (stage A of t+2; >=2 barriers since buf[nxt] last read) ----
    bf16x8 al0 = *(const bf16x8*)(cp + AT + aoffs[0]);
    bf16x8 al1 = *(const bf16x8*)(cp + AT + aoffs[1]);
    if (pf) {
      gload16(Ahi + aoff + kk2, np + wave * 512);
      gload16(Alo + aoff + kk2, np + AT + wave * 512);
    }
    __builtin_amdgcn_sched_barrier(0);
    __builtin_amdgcn_s_setprio(1);
    acc[0][0] = MFMA(al0, bh0, acc[0][0]);
    acc[0][1] = MFMA(al0, bh1, acc[0][1]);
    acc[1][0] = MFMA(al1, bh0, acc[1][0]);
    acc[1][1] = MFMA(al1, bh1, acc[1][1]);
    __builtin_amdgcn_s_setprio(0);
    __builtin_amdgcn_s_barrier();
    // ---- phase 3: hi*lo (stage B of t+2) ----
    bf16x8 bl0 = *(const bf16x8*)(cp + 2 * AT + BT + boffs[0]);
    bf16x8 bl1 = *(const bf16x8*)(cp + 2 * AT + BT + boffs[1]);
    if (pf) gload16(Bsel + boff + kk2, np + blds);
    __builtin_amdgcn_sched_barrier(0);
    __builtin_amdgcn_s_setprio(1);
    acc[0][0] = MFMA(ah0, bl0, acc[0][0]);
    acc[0][1] = MFMA(ah0, bl1, acc[0][1]);
    acc[1][0] = MFMA(ah1, bl0, acc[1][0]);
    acc[1][1] = MFMA(ah1, bl1, acc[1][1]);
    __builtin_amdgcn_s_setprio(0);
    cur = (cur + 1) % 3;                 // next-iter vmcnt+barrier closes the step
  }

#pragma unroll
  for (int m = 0; m < 2; m++) {
    const int row = m0 + wr * 32 + m * 16 + fq * 4;
#pragma unroll
    for (int n = 0; n < 2; n++) {
      const int col = n0 + wc * 32 + n * 16 + fr;
      if (ACT == 1) {
        if (col < DI) {
          const float bcol = bias[col];
#pragma unroll
          for (int j = 0; j < 4; j++)
            C[(size_t)(row + j) * ldc + col] = softplus_f(acc[m][n][j] + bcol);
        } else if (col < DI + DS) {
#pragma unroll
          for (int j = 0; j < 4; j++)
            Bmout[(size_t)(row + j) * DS + (col - DI)] = acc[m][n][j];
        }
      } else {
#pragma unroll
        for (int j = 0; j < 4; j++)
          C[(size_t)(row + j) * ldc + col] = acc[m][n][j];
      }
    }
  }
}

// ---- 4-wave variant (BM=64, BN=64), 3-phase schedule, 48KB -> 3 blocks/CU ----
__global__ __launch_bounds__(256, 6) void gemm_mfma4(
    const ushort* __restrict__ Ahi, const ushort* __restrict__ Alo, int lda,
    const ushort* __restrict__ Bhi, const ushort* __restrict__ Blo, int ldb,
    float* __restrict__ C, int ldc, int K) {
  constexpr int BM = 64, BN = 64;
  constexpr int AT = BM * 32;
  constexpr int BT = BN * 32;
  constexpr int BUF = 2 * AT + 2 * BT;   // 16KB
  __shared__ __align__(16) ushort lds[3 * BUF];

  const int tid = threadIdx.x;
  const int lane = tid & 63;
  const int wave = tid >> 6;
  const int wr = wave >> 1, wc = wave & 1;

  const int nx = gridDim.x;
  const int nwg = nx * gridDim.y;
  int bid = blockIdx.y * nx + blockIdx.x;
  bid = (bid & 7) * (nwg >> 3) + (bid >> 3);
  const int m0 = (bid / nx) * BM;
  const int n0 = (bid % nx) * BN;

  const int r0 = tid >> 2;
  const int kg = (tid & 3) ^ ((r0 >> 1) & 3);
  const size_t aoff = (size_t)(m0 + r0) * lda + kg * 8;
  const size_t boff = (size_t)(n0 + r0) * ldb + kg * 8;

  const int fr = lane & 15, fq = lane >> 4;
  const int kswz = fq ^ ((fr >> 1) & 3);
  int aoffs[2], boffs[2];
#pragma unroll
  for (int m = 0; m < 2; m++) aoffs[m] = (wr * 32 + m * 16 + fr) * 32 + kswz * 8;
#pragma unroll
  for (int n = 0; n < 2; n++) boffs[n] = (wc * 32 + n * 16 + fr) * 32 + kswz * 8;

  f32x4 acc[2][2];
#pragma unroll
  for (int m = 0; m < 2; m++)
#pragma unroll
    for (int n = 0; n < 2; n++) acc[m][n] = (f32x4){0.f, 0.f, 0.f, 0.f};

  const int nsteps = K >> 5;

#define STAGE4(bufi, kk)                                              \
  {                                                                   \
    ushort* bp = lds + (bufi) * BUF;                                  \
    gload16(Ahi + aoff + (kk), bp + wave * 512);                      \
    gload16(Alo + aoff + (kk), bp + AT + wave * 512);                 \
    gload16(Bhi + boff + (kk), bp + 2 * AT + wave * 512);             \
    gload16(Blo + boff + (kk), bp + 2 * AT + BT + wave * 512);        \
  }

  STAGE4(0, 0);
  STAGE4(1, 32);
  int cur = 0;
  for (int t = 0; t < nsteps; ++t) {
    const ushort* cp = lds + cur * BUF;
    const int nxt = (cur + 2) % 3;
    ushort* np = lds + nxt * BUF;
    const bool pf = (t + 2) < nsteps;
    const int kk2 = (t + 2) << 5;
    if (t + 1 < nsteps) asm volatile("s_waitcnt vmcnt(4)" ::: "memory");
    else                asm volatile("s_waitcnt vmcnt(0)" ::: "memory");
    __builtin_amdgcn_s_barrier();
    // phase 1: hi*hi
    bf16x8 ah0 = *(const bf16x8*)(cp + aoffs[0]);
    bf16x8 ah1 = *(const bf16x8*)(cp + aoffs[1]);
    bf16x8 bh0 = *(const bf16x8*)(cp + 2 * AT + boffs[0]);
    bf16x8 bh1 = *(const bf16x8*)(cp + 2 * AT + boffs[1]);
    __builtin_amdgcn_sched_barrier(0);
    __builtin_amdgcn_s_setprio(1);
    acc[0][0] = MFMA(ah0, bh0, acc[0][0]);
    acc[0][1] = MFMA(ah0, bh1, acc[0][1]);
    acc[1][0] = MFMA(ah1, bh0, acc[1][0]);
    acc[1][1] = MFMA(ah1, bh1, acc[1][1]);
    __builtin_amdgcn_s_setprio(0);
    __builtin_amdgcn_s_barrier();
    // phase 2: lo*hi (stage A)
    bf16x8 al0 = *(const bf16x8*)(cp + AT + aoffs[0]);
    bf16x8 al1 = *(const bf16x8*)(cp + AT + aoffs[1]);
    if (pf) {
      gload16(Ahi + aoff + kk2, np + wave * 512);
      gload16(Alo + aoff + kk2, np + AT + wave * 512);
    }
    __builtin_amdgcn_sched_barrier(0);
    __builtin_amdgcn_s_setprio(1);
    acc[0][0] = MFMA(al0, bh0, acc[0][0]);
    acc[0][1] = MFMA(al0, bh1, acc[0][1]);
    acc[1][0] = MFMA(al1, bh0, acc[1][0]);
    acc[1][1] = MFMA(al1, bh1, acc[1][1]);
    __builtin_amdgcn_s_setprio(0);
    __builtin_amdgcn_s_barrier();
    // phase 3: hi*lo (stage B)
    bf16x8 bl0 = *(const bf16x8*)(cp + 2 * AT + BT + boffs[0]);
    bf16x8 bl1 = *(const bf16x8*)(cp + 2 * AT + BT + boffs[1]);
    if (pf) {
      gload16(Bhi + boff + kk2, np + 2 * AT + wave * 512);
      gload16(Blo + boff + kk2, np + 2 * AT + BT + wave * 512);
    }
    __builtin_amdgcn_sched_barrier(0);
    __builtin_amdgcn_s_setprio(1);
    acc[0][0] = MFMA(ah0, bl0, acc[0][0]);
    acc[0][1] = MFMA(ah0, bl1, acc[0][1]);
    acc[1][0] = MFMA(ah1, bl0, acc[1][0]);
    acc[1][1] = MFMA(ah1, bl1, acc[1][1]);
    __builtin_amdgcn_s_setprio(0);
    cur = (cur + 1) % 3;
  }
#undef STAGE4

#pragma unroll
  for (int m = 0; m < 2; m++) {
    const int row = m0 + wr * 32 + m * 16 + fq * 4;
#pragma unroll
    for (int n = 0; n < 2; n++) {
      const int col = n0 + wc * 32 + n * 16 + fr;
#pragma unroll
      for (int j = 0; j < 4; j++)
        C[(size_t)(row + j) * ldc + col] = acc[m][n][j];
    }
  }
}

// depthwise causal conv (k=4) + SiLU; emits h fp32 and bf16 hi/lo split
__global__ __launch_bounds__(256) void conv_silu_kernel(
    const float* __restrict__ xz, const float* __restrict__ conv_w,
    const float* __restrict__ conv_b, float* __restrict__ h,
    ushort* __restrict__ h_hi, ushort* __restrict__ h_lo) {
  const int idx = blockIdx.x * 256 + threadIdx.x;
  const int c = idx & (DI - 1);
  const int r = idx >> 10;
  const int l = r & (L_SEQ - 1);
  const float w0 = conv_w[c * 4 + 0];
  const float w1 = conv_w[c * 4 + 1];
  const float w2 = conv_w[c * 4 + 2];
  const float w3 = conv_w[c * 4 + 3];
  const float* xp = xz + (size_t)r * (2 * DI) + c;
  float acc = conv_b[c];
  if (l >= 3) acc += xp[-3 * 2 * DI] * w0;
  if (l >= 2) acc += xp[-2 * 2 * DI] * w1;
  if (l >= 1) acc += xp[-1 * 2 * DI] * w2;
  acc += xp[0] * w3;
  const float hv = silu_f(acc);
  h[idx] = hv;
  const ushort hh = f2bf(hv);
  h_hi[idx] = hh;
  h_lo[idx] = f2bf(hv - bf2f(hh));
}

// ---- chunked selective scan, channel-per-thread ----
__global__ __launch_bounds__(256) void scan_phase1(
    const float* __restrict__ delta, const float* __restrict__ h,
    const float* __restrict__ Bm, const float* __restrict__ A_log,
    float* __restrict__ aprod, float* __restrict__ blocal) {
  __shared__ float sB[CL * DS];  // 2KB
  const int tid = threadIdx.x;
  const int bid = blockIdx.x;
  const int cblk = bid & 3;
  const int chunk = (bid >> 2) & (NC - 1);
  const int b = bid >> 8;
  const int c = cblk * 256 + tid;
  const size_t row0 = (size_t)b * L_SEQ + chunk * CL;
  ((float2*)sB)[tid] = ((const float2*)(Bm + row0 * DS))[tid];
  __syncthreads();

  float Acs[DS], state[DS];
#pragma unroll
  for (int s = 0; s < DS; s += 4) {
    float4 al = *(const float4*)(A_log + (size_t)c * DS + s);
    Acs[s + 0] = -__expf(al.x);
    Acs[s + 1] = -__expf(al.y);
    Acs[s + 2] = -__expf(al.z);
    Acs[s + 3] = -__expf(al.w);
    state[s + 0] = 0.f; state[s + 1] = 0.f; state[s + 2] = 0.f; state[s + 3] = 0.f;
  }
  const float* dp = delta + row0 * DI + c;
  const float* hp = h + row0 * DI + c;
  float sdt = 0.f;
  for (int t = 0; t < CL; ++t) {
    const float dt = dp[(size_t)t * DI];
    const float ht = hp[(size_t)t * DI];
    const float dth = dt * ht;
    sdt += dt;
#pragma unroll
    for (int s = 0; s < DS; ++s)
      state[s] = __expf(dt * Acs[s]) * state[s] + dth * sB[t * DS + s];
  }
  const size_t o = (((size_t)b * NC + chunk) * DI + c) * DS;
#pragma unroll
  for (int s = 0; s < DS; s += 4) {
    *(float4*)(aprod + o + s) = make_float4(
        __expf(Acs[s] * sdt), __expf(Acs[s + 1] * sdt),
        __expf(Acs[s + 2] * sdt), __expf(Acs[s + 3] * sdt));
    *(float4*)(blocal + o + s) = make_float4(state[s], state[s + 1], state[s + 2], state[s + 3]);
  }
}

// serial scan over chunk summaries; writes sinit IN PLACE over aprod
__global__ __launch_bounds__(256) void scan_phase2(
    float* __restrict__ aprod, const float* __restrict__ blocal) {
  const int idx = blockIdx.x * 256 + threadIdx.x;  // NB*DI*DS = 32768
  const int b = idx >> 14;
  const int cs = idx & 16383;
  float st = 0.f;
  for (int ch = 0; ch < NC; ++ch) {
    const size_t o = (size_t)(b * NC + ch) * (DI * DS) + cs;
    const float a = aprod[o];
    const float bl = blocal[o];
    aprod[o] = st;   // sinit for this chunk
    st = a * st + bl;
  }
}

// phase3: rerun chunk with init state; fused gate + bf16 hi/lo split of y.
__global__ __launch_bounds__(256) void scan_phase3(
    const float* __restrict__ delta, const float* __restrict__ h,
    const float* __restrict__ Bm, const float* __restrict__ A_log,
    const float* __restrict__ sinit, float* __restrict__ xz,
    const float* __restrict__ Dp) {
  __shared__ float sB[CL * DS];
  const int tid = threadIdx.x;
  const int bid = blockIdx.x;
  const int cblk = bid & 3;
  const int chunk = (bid >> 2) & (NC - 1);
  const int b = bid >> 8;
  const int c = cblk * 256 + tid;
  const size_t row0 = (size_t)b * L_SEQ + chunk * CL;
  ((float2*)sB)[tid] = ((const float2*)(Bm + row0 * DS))[tid];
  __syncthreads();

  float Acs[DS], state[DS];
  const size_t o = (((size_t)b * NC + chunk) * DI + c) * DS;
#pragma unroll
  for (int s = 0; s < DS; s += 4) {
    float4 al = *(const float4*)(A_log + (size_t)c * DS + s);
    Acs[s + 0] = -__expf(al.x);
    Acs[s + 1] = -__expf(al.y);
    Acs[s + 2] = -__expf(al.z);
    Acs[s + 3] = -__expf(al.w);
    float4 sv = *(const float4*)(sinit + o + s);
    state[s + 0] = sv.x; state[s + 1] = sv.y; state[s + 2] = sv.z; state[s + 3] = sv.w;
  }
  const float* dp = delta + row0 * DI + c;
  const float* hp = h + row0 * DI + c;
  const float* zp = xz + row0 * (2 * DI) + DI + c;
  ushort* yrow = (ushort*)(xz + row0 * (2 * DI)) + c;  // row stride 4096 ushorts
  const float Dc = Dp[c];
  for (int t = 0; t < CL; ++t) {
    const float dt = dp[(size_t)t * DI];
    const float ht = hp[(size_t)t * DI];
    const float z = zp[(size_t)t * (2 * DI)];
    const float dth = dt * ht;
    float yv = 0.f;
#pragma unroll
    for (int s = 0; s < DS; ++s) {
      const float bt = sB[t * DS + s];
      state[s] = __expf(dt * Acs[s]) * state[s] + dth * bt;
      yv += state[s] * bt;
    }
    const float g = (yv + Dc * ht) * silu_f(z);
    const ushort gh = f2bf(g);
    yrow[(size_t)t * 4096] = gh;
    yrow[(size_t)t * 4096 + 1024] = f2bf(g - bf2f(gh));
  }
}

extern "C" void kernel_launch(void* const* d_in, const int* in_sizes, int n_in,
                              void* d_out, int out_size, void* d_ws, size_t ws_size,
                              hipStream_t stream) {
  const float* x      = (const float*)d_in[0];
  const float* W_in   = (const float*)d_in[1];
  const float* conv_w = (const float*)d_in[2];
  const float* conv_b = (const float*)d_in[3];
  const float* W_x    = (const float*)d_in[4];
  const float* W_dt   = (const float*)d_in[5];
  const float* b_dt   = (const float*)d_in[6];
  const float* A_log  = (const float*)d_in[7];
  const float* D_par  = (const float*)d_in[8];
  const float* W_out  = (const float*)d_in[9];
  float* out = (float*)d_out;

  // ws layout (floats) — ~87 MB total (R10 layout)
  float* xz     = (float*)d_ws;                       // 8M floats
  float* h      = xz + (size_t)(8u << 20);            // 4M
  float* delta  = h + (size_t)(4u << 20);             // 4M
  float* Bm     = delta + (size_t)(4u << 20);         // 64K floats ([4096][16])
  // fused GEMM2 weight: [1088][1024] bf16 hi + lo (rows 0-1023 W_dt, 1024-1039 W_x[16:32], rest pad)
  ushort* W2hi  = (ushort*)(Bm + (size_t)(64u << 10));
  ushort* W2lo  = W2hi + (size_t)1088 * 1024;
  ushort* Wout_hi = W2lo + (size_t)1088 * 1024;
  ushort* Wout_lo = Wout_hi + (size_t)(512u << 10);
  float* xreg   = (float*)(Wout_lo + (size_t)(512u << 10));
  ushort* x_hi  = (ushort*)xreg;
  ushort* x_lo  = x_hi + (size_t)(2u << 20);
  ushort* Win_hi = x_lo + (size_t)(2u << 20);
  ushort* Win_lo = Win_hi + (size_t)(1u << 20);
  ushort* h_hi  = (ushort*)xreg;                      // overlay (x/W_in dead after GEMM1)
  ushort* h_lo  = h_hi + (size_t)(4u << 20);
  float* aprod  = xreg;                               // overlay (h_hi/h_lo dead after GEMM2)
  float* blocal = aprod + (size_t)(2u << 20);         // NB*NC*DI*DS = 2M floats each
  ushort* y_hi  = (ushort*)xz;                        // xi-cols overlay, lda 4096
  ushort* y_lo  = y_hi + 1024;

  const int rows = NB * L_SEQ;  // 4096

  // 0) all bf16 hi/lo splits in one launch (2048+1024+1024+16+512 = 4624 blocks)
  split_all<<<4624, 256, 0, stream>>>(
      x, x_hi, x_lo, W_in, Win_hi, Win_lo, W_dt, W2hi, W2lo,
      W_x + DS * DI, W2hi + (size_t)DI * DI, W2lo + (size_t)DI * DI,
      W_out, Wout_hi, Wout_lo);

  // 1) xz = x @ W_in^T   M=4096 N=2048 K=512   (grid 32x32 = 1024)
  gemm_mfma8<0><<<dim3(32, 32), 512, 0, stream>>>(
      x_hi, x_lo, DM, Win_hi, Win_lo, DM, nullptr, xz, 2 * DI, nullptr, DM);
  // 2) conv + silu -> h (+ hi/lo)
  conv_silu_kernel<<<(rows * DI) / 256, 256, 0, stream>>>(xz, conv_w, conv_b, h, h_hi, h_lo);
  // 3) fused delta+Bmat GEMM: [4096]x[1088]x[1024]  (grid 17x32 = 544)
  gemm_mfma8<1><<<dim3(17, 32), 512, 0, stream>>>(
      h_hi, h_lo, DI, W2hi, W2lo, DI, b_dt, delta, DI, Bm, DI);
  // 4) chunked scan
  scan_phase1<<<NB * NC * (DI / 256), 256, 0, stream>>>(delta, h, Bm, A_log, aprod, blocal);
  scan_phase2<<<(NB * DI * DS) / 256, 256, 0, stream>>>(aprod, blocal);
  scan_phase3<<<NB * NC * (DI / 256), 256, 0, stream>>>(delta, h, Bm, A_log, aprod, xz, D_par);
  // 5) out = y @ W_out^T   M=4096 N=512 K=1024   (grid 8x64 = 512)
  gemm_mfma4<<<dim3(8, 64), 256, 0, stream>>>(
      y_hi, y_lo, 4096, Wout_hi, Wout_lo, DI, out, DM, DI);
}

// Round 13
// 200.492 us; speedup vs baseline: 1.0654x; 1.0062x over previous
//
#include <hip/hip_runtime.h>
#include <cstddef>
#include <cstdint>

#define NB 2
#define L_SEQ 2048
#define DM 512
#define DS 16
#define DI 1024
#define NC 64
#define CL (L_SEQ/NC)   // 32

typedef __attribute__((ext_vector_type(4))) float f32x4;
typedef __attribute__((ext_vector_type(8))) short bf16x8;

__device__ __forceinline__ float softplus_f(float x) {
  return (x > 20.f) ? x : log1pf(expf(x));
}
__device__ __forceinline__ float silu_f(float x) {
  return x / (1.f + expf(-x));
}
__device__ __forceinline__ ushort f2bf(float f) {
  uint32_t u = __float_as_uint(f);
  return (ushort)((u + 0x7fffu + ((u >> 16) & 1u)) >> 16);
}
__device__ __forceinline__ float bf2f(ushort h) {
  return __uint_as_float(((uint32_t)h) << 16);
}

__device__ __forceinline__ void gload16(const void* g, ushort* lds_wave_base) {
  __builtin_amdgcn_global_load_lds(
      (const __attribute__((address_space(1))) void*)g,
      (__attribute__((address_space(3))) void*)lds_wave_base, 16, 0, 0);
}

__device__ __forceinline__ void split4(const float4 v, ushort4* hi, ushort4* lo) {
  ushort h0 = f2bf(v.x), h1 = f2bf(v.y), h2 = f2bf(v.z), h3 = f2bf(v.w);
  *hi = make_ushort4(h0, h1, h2, h3);
  *lo = make_ushort4(f2bf(v.x - bf2f(h0)), f2bf(v.y - bf2f(h1)),
                     f2bf(v.z - bf2f(h2)), f2bf(v.w - bf2f(h3)));
}

// one kernel, 5 segments: x, W_in, W_dt, W_x-tail, W_out
__global__ __launch_bounds__(256) void split_all(
    const float* __restrict__ x,    ushort* __restrict__ xh,  ushort* __restrict__ xl,
    const float* __restrict__ win,  ushort* __restrict__ wih, ushort* __restrict__ wil,
    const float* __restrict__ wdt,  ushort* __restrict__ wdh, ushort* __restrict__ wdl,
    const float* __restrict__ wx,   ushort* __restrict__ wxh, ushort* __restrict__ wxl,
    const float* __restrict__ wout, ushort* __restrict__ woh, ushort* __restrict__ wol) {
  int bi = blockIdx.x;
  const float* in; ushort* hi; ushort* lo; int i;
  if (bi < 2048)      { in = x;    hi = xh;  lo = xl;  i = bi * 256 + threadIdx.x; }
  else if (bi < 3072) { in = win;  hi = wih; lo = wil; i = (bi - 2048) * 256 + threadIdx.x; }
  else if (bi < 4096) { in = wdt;  hi = wdh; lo = wdl; i = (bi - 3072) * 256 + threadIdx.x; }
  else if (bi < 4112) { in = wx;   hi = wxh; lo = wxl; i = (bi - 4096) * 256 + threadIdx.x; }
  else                { in = wout; hi = woh; lo = wol; i = (bi - 4112) * 256 + threadIdx.x; }
  float4 v = ((const float4*)in)[i];
  ushort4 h4, l4;
  split4(v, &h4, &l4);
  ((ushort4*)hi)[i] = h4;
  ((ushort4*)lo)[i] = l4;
}

#define MFMA(a, b, c) __builtin_amdgcn_mfma_f32_16x16x32_bf16((a), (b), (c), 0, 0, 0)

// ---- 8-wave split-bf16 MFMA GEMM (BM=128, BN=64), R7-proven loop ----
// 3 LDS buffers (72KB -> 2 blocks/CU, 16 waves/CU), 2-deep prefetch,
// ONE s_barrier + counted vmcnt(3) per K-step, single 12-MFMA cluster.
// Each thread stages exactly 3 gloads: Ahi, Alo, one of Bhi/Blo (by wave).
// ACT==1: cols<1024 -> softplus(+bias); cols 1024..1039 -> Bmout; rest discard.
template <int ACT>
__global__ __launch_bounds__(512, 4) void gemm_mfma8(
    const ushort* __restrict__ Ahi, const ushort* __restrict__ Alo, int lda,
    const ushort* __restrict__ Bhi, const ushort* __restrict__ Blo, int ldb,
    const float* __restrict__ bias, float* __restrict__ C, int ldc,
    float* __restrict__ Bmout, int K) {
  constexpr int BM = 128, BN = 64;
  constexpr int AT = BM * 32;           // 4096 ushorts (8KB)
  constexpr int BT = BN * 32;           // 2048 ushorts (4KB)
  constexpr int BUF = 2 * AT + 2 * BT;  // 24KB
  constexpr int MR = 2, NR = 2;
  __shared__ __align__(16) ushort lds[3 * BUF];  // 72KB

  const int tid = threadIdx.x;
  const int lane = tid & 63;
  const int wave = tid >> 6;            // 0..7
  const int wr = wave >> 1;             // 0..3
  const int wc = wave & 1;              // 0..1

  // bijective XCD swizzle (all launches have nwg % 8 == 0)
  const int nx = gridDim.x;
  const int nwg = nx * gridDim.y;
  int bid = blockIdx.y * nx + blockIdx.x;
  bid = (bid & 7) * (nwg >> 3) + (bid >> 3);
  const int m0 = (bid / nx) * BM;
  const int n0 = (bid % nx) * BN;

  // A staging: thread -> row tid>>2 (0..127), k-slot (tid&3) pre-swizzled
  const int ra = tid >> 2;
  const int kga = (tid & 3) ^ ((ra >> 1) & 3);
  const size_t aoff = (size_t)(m0 + ra) * lda + kga * 8;
  // B staging: tq = tid&255 -> row tq>>2 (0..63); waves 0-3 stage Bhi, 4-7 Blo
  const int tq = tid & 255;
  const int rb = tq >> 2;
  const int kgb = (tq & 3) ^ ((rb >> 1) & 3);
  const size_t boff = (size_t)(n0 + rb) * ldb + kgb * 8;
  const ushort* Bsel = (wave < 4) ? Bhi : Blo;
  const int blds = 2 * AT + ((wave < 4) ? wave * 512 : BT + (wave - 4) * 512);

  // fragment reads: row = wr*32 + m*16 + fr; k-slot = fq ^ ((fr>>1)&3)
  const int fr = lane & 15, fq = lane >> 4;
  const int kswz = fq ^ ((fr >> 1) & 3);
  int aoffs[MR], boffs[NR];
#pragma unroll
  for (int m = 0; m < MR; m++) aoffs[m] = (wr * 32 + m * 16 + fr) * 32 + kswz * 8;
#pragma unroll
  for (int n = 0; n < NR; n++) boffs[n] = (wc * 32 + n * 16 + fr) * 32 + kswz * 8;

  f32x4 acc[MR][NR];
#pragma unroll
  for (int m = 0; m < MR; m++)
#pragma unroll
    for (int n = 0; n < NR; n++) acc[m][n] = (f32x4){0.f, 0.f, 0.f, 0.f};

  const int nsteps = K >> 5;

#define STAGE(base, kk)                                     \
  {                                                         \
    ushort* bp = (base);                                    \
    gload16(Ahi + aoff + (kk), bp + wave * 512);            \
    gload16(Alo + aoff + (kk), bp + AT + wave * 512);       \
    gload16(Bsel + boff + (kk), bp + blds);                 \
  }

#define COMPUTE(base)                                                          \
  {                                                                            \
    const ushort* cp = (base);                                                 \
    bf16x8 ah[MR], al[MR], bh[NR], bl[NR];                                     \
    _Pragma("unroll")                                                          \
    for (int m = 0; m < MR; m++) ah[m] = *(const bf16x8*)(cp + aoffs[m]);      \
    _Pragma("unroll")                                                          \
    for (int m = 0; m < MR; m++) al[m] = *(const bf16x8*)(cp + AT + aoffs[m]); \
    _Pragma("unroll")                                                          \
    for (int n = 0; n < NR; n++) bh[n] = *(const bf16x8*)(cp + 2 * AT + boffs[n]); \
    _Pragma("unroll")                                                          \
    for (int n = 0; n < NR; n++) bl[n] = *(const bf16x8*)(cp + 2 * AT + BT + boffs[n]); \
    _Pragma("unroll")                                                          \
    for (int m = 0; m < MR; m++)                                               \
      _Pragma("unroll")                                                        \
      for (int n = 0; n < NR; n++)                                             \
        acc[m][n] = MFMA(ah[m], bh[n], acc[m][n]);                             \
    _Pragma("unroll")                                                          \
    for (int m = 0; m < MR; m++)                                               \
      _Pragma("unroll")                                                        \
      for (int n = 0; n < NR; n++)                                             \
        acc[m][n] = MFMA(al[m], bh[n], acc[m][n]);                             \
    _Pragma("unroll")                                                          \
    for (int m = 0; m < MR; m++)                                               \
      _Pragma("unroll")                                                        \
      for (int n = 0; n < NR; n++)                                             \
        acc[m][n] = MFMA(ah[m], bl[n], acc[m][n]);                             \
  }

  STAGE(lds, 0);
  STAGE(lds + BUF, 32);
  int ocur = 0, onext = BUF, ofar = 2 * BUF;
  for (int t = 0; t < nsteps; ++t) {
    if (t == nsteps - 1) asm volatile("s_waitcnt vmcnt(0)" ::: "memory");
    else                 asm volatile("s_waitcnt vmcnt(3)" ::: "memory");
    __builtin_amdgcn_s_barrier();       // buf[t] staged by all waves; buf[t-1] reads done
    if (t + 2 < nsteps) STAGE(lds + ofar, (t + 2) << 5);  // stays in flight across barrier
    COMPUTE(lds + ocur);
    int tmp = ocur; ocur = onext; onext = ofar; ofar = tmp;
  }
#undef STAGE
#undef COMPUTE

#pragma unroll
  for (int m = 0; m < MR; m++) {
    const int row = m0 + wr * 32 + m * 16 + fq * 4;
#pragma unroll
    for (int n = 0; n < NR; n++) {
      const int col = n0 + wc * 32 + n * 16 + fr;
      if (ACT == 1) {
        if (col < DI) {                  // delta columns
          const float bcol = bias[col];
#pragma unroll
          for (int j = 0; j < 4; j++)
            C[(size_t)(row + j) * ldc + col] = softplus_f(acc[m][n][j] + bcol);
        } else if (col < DI + DS) {      // Bmat columns
#pragma unroll
          for (int j = 0; j < 4; j++)
            Bmout[(size_t)(row + j) * DS + (col - DI)] = acc[m][n][j];
        }                                // else: pad columns, discard
      } else {
#pragma unroll
        for (int j = 0; j < 4; j++)
          C[(size_t)(row + j) * ldc + col] = acc[m][n][j];
      }
    }
  }
}

// ---- 4-wave variant (BM=64, BN=64), same R7 loop, 48KB -> 3 blocks/CU ----
__global__ __launch_bounds__(256, 3) void gemm_mfma4(
    const ushort* __restrict__ Ahi, const ushort* __restrict__ Alo, int lda,
    const ushort* __restrict__ Bhi, const ushort* __restrict__ Blo, int ldb,
    float* __restrict__ C, int ldc, int K) {
  constexpr int BM = 64, BN = 64;
  constexpr int AT = BM * 32;
  constexpr int BT = BN * 32;
  constexpr int BUF = 2 * AT + 2 * BT;   // 16KB
  constexpr int MR = 2, NR = 2;
  __shared__ __align__(16) ushort lds[3 * BUF];  // 48KB

  const int tid = threadIdx.x;
  const int lane = tid & 63;
  const int wave = tid >> 6;
  const int wr = wave >> 1, wc = wave & 1;

  const int nx = gridDim.x;
  const int nwg = nx * gridDim.y;
  int bid = blockIdx.y * nx + blockIdx.x;
  bid = (bid & 7) * (nwg >> 3) + (bid >> 3);
  const int m0 = (bid / nx) * BM;
  const int n0 = (bid % nx) * BN;

  const int r0 = tid >> 2;
  const int kg = (tid & 3) ^ ((r0 >> 1) & 3);
  const size_t aoff = (size_t)(m0 + r0) * lda + kg * 8;
  const size_t boff = (size_t)(n0 + r0) * ldb + kg * 8;

  const int fr = lane & 15, fq = lane >> 4;
  const int kswz = fq ^ ((fr >> 1) & 3);
  int aoffs[MR], boffs[NR];
#pragma unroll
  for (int m = 0; m < MR; m++) aoffs[m] = (wr * 32 + m * 16 + fr) * 32 + kswz * 8;
#pragma unroll
  for (int n = 0; n < NR; n++) boffs[n] = (wc * 32 + n * 16 + fr) * 32 + kswz * 8;

  f32x4 acc[MR][NR];
#pragma unroll
  for (int m = 0; m < MR; m++)
#pragma unroll
    for (int n = 0; n < NR; n++) acc[m][n] = (f32x4){0.f, 0.f, 0.f, 0.f};

  const int nsteps = K >> 5;

#define STAGE4(base, kk)                                          \
  {                                                               \
    ushort* bp = (base);                                          \
    gload16(Ahi + aoff + (kk), bp + wave * 512);                  \
    gload16(Alo + aoff + (kk), bp + AT + wave * 512);             \
    gload16(Bhi + boff + (kk), bp + 2 * AT + wave * 512);         \
    gload16(Blo + boff + (kk), bp + 2 * AT + BT + wave * 512);    \
  }

#define COMPUTE4(base)                                                         \
  {                                                                            \
    const ushort* cp = (base);                                                 \
    bf16x8 ah[MR], al[MR], bh[NR], bl[NR];                                     \
    _Pragma("unroll")                                                          \
    for (int m = 0; m < MR; m++) ah[m] = *(const bf16x8*)(cp + aoffs[m]);      \
    _Pragma("unroll")                                                          \
    for (int m = 0; m < MR; m++) al[m] = *(const bf16x8*)(cp + AT + aoffs[m]); \
    _Pragma("unroll")                                                          \
    for (int n = 0; n < NR; n++) bh[n] = *(const bf16x8*)(cp + 2 * AT + boffs[n]); \
    _Pragma("unroll")                                                          \
    for (int n = 0; n < NR; n++) bl[n] = *(const bf16x8*)(cp + 2 * AT + BT + boffs[n]); \
    _Pragma("unroll")                                                          \
    for (int m = 0; m < MR; m++)                                               \
      _Pragma("unroll")                                                        \
      for (int n = 0; n < NR; n++)                                             \
        acc[m][n] = MFMA(ah[m], bh[n], acc[m][n]);                             \
    _Pragma("unroll")                                                          \
    for (int m = 0; m < MR; m++)                                               \
      _Pragma("unroll")                                                        \
      for (int n = 0; n < NR; n++)                                             \
        acc[m][n] = MFMA(al[m], bh[n], acc[m][n]);                             \
    _Pragma("unroll")                                                          \
    for (int m = 0; m < MR; m++)                                               \
      _Pragma("unroll")                                                        \
      for (int n = 0; n < NR; n++)                                             \
        acc[m][n] = MFMA(ah[m], bl[n], acc[m][n]);                             \
  }

  STAGE4(lds, 0);
  STAGE4(lds + BUF, 32);
  int ocur = 0, onext = BUF, ofar = 2 * BUF;
  for (int t = 0; t < nsteps; ++t) {
    if (t == nsteps - 1) asm volatile("s_waitcnt vmcnt(0)" ::: "memory");
    else                 asm volatile("s_waitcnt vmcnt(4)" ::: "memory");
    __builtin_amdgcn_s_barrier();
    if (t + 2 < nsteps) STAGE4(lds + ofar, (t + 2) << 5);
    COMPUTE4(lds + ocur);
    int tmp = ocur; ocur = onext; onext = ofar; ofar = tmp;
  }
#undef STAGE4
#undef COMPUTE4

#pragma unroll
  for (int m = 0; m < MR; m++) {
    const int row = m0 + wr * 32 + m * 16 + fq * 4;
#pragma unroll
    for (int n = 0; n < NR; n++) {
      const int col = n0 + wc * 32 + n * 16 + fr;
#pragma unroll
      for (int j = 0; j < 4; j++)
        C[(size_t)(row + j) * ldc + col] = acc[m][n][j];
    }
  }
}

// depthwise causal conv (k=4) + SiLU; emits h fp32 and bf16 hi/lo split
__global__ __launch_bounds__(256) void conv_silu_kernel(
    const float* __restrict__ xz, const float* __restrict__ conv_w,
    const float* __restrict__ conv_b, float* __restrict__ h,
    ushort* __restrict__ h_hi, ushort* __restrict__ h_lo) {
  const int idx = blockIdx.x * 256 + threadIdx.x;
  const int c = idx & (DI - 1);
  const int r = idx >> 10;
  const int l = r & (L_SEQ - 1);
  const float w0 = conv_w[c * 4 + 0];
  const float w1 = conv_w[c * 4 + 1];
  const float w2 = conv_w[c * 4 + 2];
  const float w3 = conv_w[c * 4 + 3];
  const float* xp = xz + (size_t)r * (2 * DI) + c;
  float acc = conv_b[c];
  if (l >= 3) acc += xp[-3 * 2 * DI] * w0;
  if (l >= 2) acc += xp[-2 * 2 * DI] * w1;
  if (l >= 1) acc += xp[-1 * 2 * DI] * w2;
  acc += xp[0] * w3;
  const float hv = silu_f(acc);
  h[idx] = hv;
  const ushort hh = f2bf(hv);
  h_hi[idx] = hh;
  h_lo[idx] = f2bf(hv - bf2f(hh));
}

// ---- chunked selective scan, channel-per-thread ----
__global__ __launch_bounds__(256) void scan_phase1(
    const float* __restrict__ delta, const float* __restrict__ h,
    const float* __restrict__ Bm, const float* __restrict__ A_log,
    float* __restrict__ aprod, float* __restrict__ blocal) {
  __shared__ float sB[CL * DS];  // 2KB
  const int tid = threadIdx.x;
  const int bid = blockIdx.x;
  const int cblk = bid & 3;
  const int chunk = (bid >> 2) & (NC - 1);
  const int b = bid >> 8;
  const int c = cblk * 256 + tid;
  const size_t row0 = (size_t)b * L_SEQ + chunk * CL;
  ((float2*)sB)[tid] = ((const float2*)(Bm + row0 * DS))[tid];
  __syncthreads();

  float Acs[DS], state[DS];
#pragma unroll
  for (int s = 0; s < DS; s += 4) {
    float4 al = *(const float4*)(A_log + (size_t)c * DS + s);
    Acs[s + 0] = -__expf(al.x);
    Acs[s + 1] = -__expf(al.y);
    Acs[s + 2] = -__expf(al.z);
    Acs[s + 3] = -__expf(al.w);
    state[s + 0] = 0.f; state[s + 1] = 0.f; state[s + 2] = 0.f; state[s + 3] = 0.f;
  }
  const float* dp = delta + row0 * DI + c;
  const float* hp = h + row0 * DI + c;
  float sdt = 0.f;
  for (int t = 0; t < CL; ++t) {
    const float dt = dp[(size_t)t * DI];
    const float ht = hp[(size_t)t * DI];
    const float dth = dt * ht;
    sdt += dt;
#pragma unroll
    for (int s = 0; s < DS; ++s)
      state[s] = __expf(dt * Acs[s]) * state[s] + dth * sB[t * DS + s];
  }
  const size_t o = (((size_t)b * NC + chunk) * DI + c) * DS;
#pragma unroll
  for (int s = 0; s < DS; s += 4) {
    *(float4*)(aprod + o + s) = make_float4(
        __expf(Acs[s] * sdt), __expf(Acs[s + 1] * sdt),
        __expf(Acs[s + 2] * sdt), __expf(Acs[s + 3] * sdt));
    *(float4*)(blocal + o + s) = make_float4(state[s], state[s + 1], state[s + 2], state[s + 3]);
  }
}

// serial scan over chunk summaries; writes sinit IN PLACE over aprod
__global__ __launch_bounds__(256) void scan_phase2(
    float* __restrict__ aprod, const float* __restrict__ blocal) {
  const int idx = blockIdx.x * 256 + threadIdx.x;  // NB*DI*DS = 32768
  const int b = idx >> 14;
  const int cs = idx & 16383;
  float st = 0.f;
  for (int ch = 0; ch < NC; ++ch) {
    const size_t o = (size_t)(b * NC + ch) * (DI * DS) + cs;
    const float a = aprod[o];
    const float bl = blocal[o];
    aprod[o] = st;   // sinit for this chunk
    st = a * st + bl;
  }
}

// phase3: rerun chunk with init state; fused gate + bf16 hi/lo split of y.
__global__ __launch_bounds__(256) void scan_phase3(
    const float* __restrict__ delta, const float* __restrict__ h,
    const float* __restrict__ Bm, const float* __restrict__ A_log,
    const float* __restrict__ sinit, float* __restrict__ xz,
    const float* __restrict__ Dp) {
  __shared__ float sB[CL * DS];
  const int tid = threadIdx.x;
  const int bid = blockIdx.x;
  const int cblk = bid & 3;
  const int chunk = (bid >> 2) & (NC - 1);
  const int b = bid >> 8;
  const int c = cblk * 256 + tid;
  const size_t row0 = (size_t)b * L_SEQ + chunk * CL;
  ((float2*)sB)[tid] = ((const float2*)(Bm + row0 * DS))[tid];
  __syncthreads();

  float Acs[DS], state[DS];
  const size_t o = (((size_t)b * NC + chunk) * DI + c) * DS;
#pragma unroll
  for (int s = 0; s < DS; s += 4) {
    float4 al = *(const float4*)(A_log + (size_t)c * DS + s);
    Acs[s + 0] = -__expf(al.x);
    Acs[s + 1] = -__expf(al.y);
    Acs[s + 2] = -__expf(al.z);
    Acs[s + 3] = -__expf(al.w);
    float4 sv = *(const float4*)(sinit + o + s);
    state[s + 0] = sv.x; state[s + 1] = sv.y; state[s + 2] = sv.z; state[s + 3] = sv.w;
  }
  const float* dp = delta + row0 * DI + c;
  const float* hp = h + row0 * DI + c;
  const float* zp = xz + row0 * (2 * DI) + DI + c;
  ushort* yrow = (ushort*)(xz + row0 * (2 * DI)) + c;  // row stride 4096 ushorts
  const float Dc = Dp[c];
  for (int t = 0; t < CL; ++t) {
    const float dt = dp[(size_t)t * DI];
    const float ht = hp[(size_t)t * DI];
    const float z = zp[(size_t)t * (2 * DI)];
    const float dth = dt * ht;
    float yv = 0.f;
#pragma unroll
    for (int s = 0; s < DS; ++s) {
      const float bt = sB[t * DS + s];
      state[s] = __expf(dt * Acs[s]) * state[s] + dth * bt;
      yv += state[s] * bt;
    }
    const float g = (yv + Dc * ht) * silu_f(z);
    const ushort gh = f2bf(g);
    yrow[(size_t)t * 4096] = gh;
    yrow[(size_t)t * 4096 + 1024] = f2bf(g - bf2f(gh));
  }
}

extern "C" void kernel_launch(void* const* d_in, const int* in_sizes, int n_in,
                              void* d_out, int out_size, void* d_ws, size_t ws_size,
                              hipStream_t stream) {
  const float* x      = (const float*)d_in[0];
  const float* W_in   = (const float*)d_in[1];
  const float* conv_w = (const float*)d_in[2];
  const float* conv_b = (const float*)d_in[3];
  const float* W_x    = (const float*)d_in[4];
  const float* W_dt   = (const float*)d_in[5];
  const float* b_dt   = (const float*)d_in[6];
  const float* A_log  = (const float*)d_in[7];
  const float* D_par  = (const float*)d_in[8];
  const float* W_out  = (const float*)d_in[9];
  float* out = (float*)d_out;

  // ws layout (floats) — ~87 MB total
  float* xz     = (float*)d_ws;                       // 8M floats
  float* h      = xz + (size_t)(8u << 20);            // 4M
  float* delta  = h + (size_t)(4u << 20);             // 4M
  float* Bm     = delta + (size_t)(4u << 20);         // 64K floats ([4096][16])
  // fused GEMM2 weight: [1088][1024] bf16 hi + lo (rows 0-1023 W_dt, 1024-1039 W_x[16:32], rest pad)
  ushort* W2hi  = (ushort*)(Bm + (size_t)(64u << 10));
  ushort* W2lo  = W2hi + (size_t)1088 * 1024;
  ushort* Wout_hi = W2lo + (size_t)1088 * 1024;
  ushort* Wout_lo = Wout_hi + (size_t)(512u << 10);
  float* xreg   = (float*)(Wout_lo + (size_t)(512u << 10));
  ushort* x_hi  = (ushort*)xreg;
  ushort* x_lo  = x_hi + (size_t)(2u << 20);
  ushort* Win_hi = x_lo + (size_t)(2u << 20);
  ushort* Win_lo = Win_hi + (size_t)(1u << 20);
  ushort* h_hi  = (ushort*)xreg;                      // overlay (x/W_in dead after GEMM1)
  ushort* h_lo  = h_hi + (size_t)(4u << 20);
  float* aprod  = xreg;                               // overlay (h_hi/h_lo dead after GEMM2)
  float* blocal = aprod + (size_t)(2u << 20);         // NB*NC*DI*DS = 2M floats each
  ushort* y_hi  = (ushort*)xz;                        // xi-cols overlay, lda 4096
  ushort* y_lo  = y_hi + 1024;

  const int rows = NB * L_SEQ;  // 4096

  // 0) all bf16 hi/lo splits in one launch
  split_all<<<4624, 256, 0, stream>>>(
      x, x_hi, x_lo, W_in, Win_hi, Win_lo, W_dt, W2hi, W2lo,
      W_x + DS * DI, W2hi + (size_t)DI * DI, W2lo + (size_t)DI * DI,
      W_out, Wout_hi, Wout_lo);

  // 1) xz = x @ W_in^T   M=4096 N=2048 K=512   (grid 32x32 = 1024)
  gemm_mfma8<0><<<dim3(32, 32), 512, 0, stream>>>(
      x_hi, x_lo, DM, Win_hi, Win_lo, DM, nullptr, xz, 2 * DI, nullptr, DM);
  // 2) conv + silu -> h (+ hi/lo)
  conv_silu_kernel<<<(rows * DI) / 256, 256, 0, stream>>>(xz, conv_w, conv_b, h, h_hi, h_lo);
  // 3) fused delta+Bmat GEMM: [4096]x[1088]x[1024]  (grid 17x32 = 544)
  gemm_mfma8<1><<<dim3(17, 32), 512, 0, stream>>>(
      h_hi, h_lo, DI, W2hi, W2lo, DI, b_dt, delta, DI, Bm, DI);
  // 4) chunked scan
  scan_phase1<<<NB * NC * (DI / 256), 256, 0, stream>>>(delta, h, Bm, A_log, aprod, blocal);
  scan_phase2<<<(NB * DI * DS) / 256, 256, 0, stream>>>(aprod, blocal);
  scan_phase3<<<NB * NC * (DI / 256), 256, 0, stream>>>(delta, h, Bm, A_log, aprod, xz, D_par);
  // 5) out = y @ W_out^T   M=4096 N=512 K=1024   (grid 8x64 = 512)
  gemm_mfma4<<<dim3(8, 64), 256, 0, stream>>>(
      y_hi, y_lo, 4096, Wout_hi, Wout_lo, DI, out, DM, DI);
}